// Round 8
// baseline (144.058 us; speedup 1.0000x reference)
//
#include <hip/hip_runtime.h>
#include <math.h>

#define IMG   512
#define NFILT 32
#define NPAIR 16
#define PI_F  3.14159265358979323846f
#define GS    104      // gray LDS row stride in halves (208 B)

typedef _Float16 v8h __attribute__((ext_vector_type(8)));
typedef _Float16 v4h __attribute__((ext_vector_type(4)));
typedef float    v4f __attribute__((ext_vector_type(4)));

#define MF32(a, b, c) __builtin_amdgcn_mfma_f32_16x16x32_f16((a), (b), (c), 0, 0, 0)

// K=16 MFMA: builtin name varies across ROCm (legacy no-underscore vs new);
// guard with __has_builtin, final fallback = raw ISA (cdna4_isa.md §10 lists
// v_mfma_f32_16x16x16_f16 on gfx950).
#if __has_builtin(__builtin_amdgcn_mfma_f32_16x16x16f16)
__device__ __forceinline__ v4f mf16(v4h a, v4h b, v4f c) {
    return __builtin_amdgcn_mfma_f32_16x16x16f16(a, b, c, 0, 0, 0);
}
#elif __has_builtin(__builtin_amdgcn_mfma_f32_16x16x16_f16)
__device__ __forceinline__ v4f mf16(v4h a, v4h b, v4f c) {
    return __builtin_amdgcn_mfma_f32_16x16x16_f16(a, b, c, 0, 0, 0);
}
#else
__device__ __forceinline__ v4f mf16(v4h a, v4h b, v4f c) {
    asm("v_mfma_f32_16x16x16_f16 %0, %1, %2, %0" : "+v"(c) : "v"(a), "v"(b));
    return c;
}
#endif
#define MF16(a, b, c) mf16((a), (b), (c))

__device__ __forceinline__ unsigned pkrtz(float a, float b) {
    typedef __fp16 f16x2 __attribute__((ext_vector_type(2)));
    union { f16x2 h; unsigned u; } x;
    x.h = __builtin_amdgcn_cvt_pkrtz(a, b);
    return x.u;
}

template <int CTRL>
__device__ __forceinline__ float dpp_add(float v) {
    int t = __builtin_amdgcn_update_dpp(0, __float_as_int(v), CTRL, 0xf, 0xf, true);
    return v + __int_as_float(t);
}

#if __has_builtin(__builtin_amdgcn_sqrtf)
__device__ __forceinline__ float fsqrt(float x) { return __builtin_amdgcn_sqrtf(x); }
#else
__device__ __forceinline__ float fsqrt(float x) { return sqrtf(x); }
#endif

__device__ __forceinline__ v8h ldfrag(const uint4* p) {
    union { uint4 u; v8h h; } x; x.u = *p; return x.h;
}
__device__ __forceinline__ v4h ldfrag2(const uint2* p) {
    union { uint2 u; v4h h; } x; x.u = *p; return x.h;
}
// f32 C/D tile (row=4g+r, col=nn) -> f16 B-operand fragment for 16x16x16 MFMA
// (k=4g+e, col=nn).  Layout identity: NO cross-lane movement needed.
__device__ __forceinline__ v4h pk4(v4f a) {
    union { unsigned u[2]; v4h h; } x;
    x.u[0] = pkrtz(a[0], a[1]);
    x.u[1] = pkrtz(a[2], a[3]);
    return x.h;
}

// ---------------------------------------------------------------------------
// tabs layout (dwords): [filter:32][table:5][copy:8][block:20][dw:4]
//   tables: 0 g_re, 1 g_im, 2 f_re, 3 f_im, 4 -f_im (tbl4 kept for layout)
//   copy c, block i holds halves tap(8*i-64+c .. +7); tap(t)=0 unless 0<=t<32.
// The 8 phase copies let ANY aligned 4- or 8-tap window be loaded directly:
//   uint4 at (u&7)*20+(u>>3) + B*4        -> taps u+32B .. u+32B+7
//   uint2 at 2*((u&7)*20+(u>>3)) + 4*m    -> taps u+16m .. u+16m+3
// ---------------------------------------------------------------------------
__global__ void make_tables(unsigned* __restrict__ tabs) {
    __shared__ _Float16 P[5][168];      // P[tbl][p] = tap(p-64), zero-padded
    const int fo = blockIdx.x;
    const int tid = threadIdx.x;
    for (int e = tid; e < 5 * 168; e += 256) ((_Float16*)P)[e] = (_Float16)0.0f;
    __syncthreads();
    if (tid < 160) {
        int tbl = tid >> 5, t = tid & 31;
        int s = (fo >> 3) + 1, o = fo & 7;
        float theta = (float)o * (PI_F / 7.0f);      // linspace(0, pi, 8)
        float sf = (float)s * 2.0f;                  // scale * SIGMA
        float kf = 2.0f * PI_F / ((float)s * sf);
        float a = kf * cosf(theta), b = kf * sinf(theta);
        float d = (float)(t - 16);
        float env = expf(-0.5f * d * d / (sf * sf));
        float v;
        switch (tbl) {
            case 0: v =  env * cosf(b * d); break;
            case 1: v =  env * sinf(b * d); break;
            case 2: v =  env * cosf(a * d); break;
            case 3: v =  env * sinf(a * d); break;
            default: v = -env * sinf(a * d); break;
        }
        P[tbl][t + 64] = (_Float16)v;
    }
    __syncthreads();
    unsigned* dst = tabs + (size_t)fo * 3200;
    for (int e = tid; e < 3200; e += 256) {
        int tbl  = e / 640;  int rem2 = e - tbl * 640;
        int copy = rem2 / 80; int idw = rem2 - copy * 80;
        int p0 = (idw >> 2) * 8 + copy + (idw & 3) * 2;   // = t0 + 64
        union { unsigned u; _Float16 h[2]; } p;
        p.h[0] = P[tbl][p0];
        p.h[1] = P[tbl][p0 + 1];
        dst[e] = p.u;
    }
}

// ---------------------------------------------------------------------------
// R19c (3rd submit; prior two runs died at container level, no kernel data;
// MF16 builtin now __has_builtin-guarded as the only new construct vs known-
// good rounds): BARRIER-FREE main loop.  Each wave (r4, hh) is self-contained:
// pass A computes the T tiles ITS pass B needs (m-tiles 2b0..2b0+3 x c-tiles
// 2hh..2hh+1) into REGISTERS; pk4 converts each f32 C/D tile into a ready
// 16x16x16 B-fragment (layout identity, no lane exchange).  Pass B contracts
// with K=16 MFMAs (F as 4-tap uint2 fragments).  Redundant pass-A compute
// (2 waves share each T group) buys: no T LDS, no s1st, ZERO barriers after
// staging.  LDS 20 KB.  S1 stored directly to global.
// ---------------------------------------------------------------------------
__launch_bounds__(512, 4)
__global__ void conv_kernel(const float* __restrict__ x,
                            const uint4* __restrict__ tabs,
                            float* __restrict__ s0out,
                            float* __restrict__ s1out) {
    __shared__ _Float16 gray[96 * GS];       // 19968 B (only LDS user)

    const int bx = blockIdx.x;
    const int n  = bx >> 6;                  // image
    const int t6 = bx & 63;                  // tile
    const int ty = t6 >> 3, tx = t6 & 7;
    const int r0g = ty * 64 - 16;
    const int c0g = tx * 64 - 16;            // 16-aligned -> float4-aligned
    const int tid = threadIdx.x;

    const int lane = tid & 63;
    const int w    = tid >> 6;
    const int r4   = w & 3;                  // out M-tile
    const int hh   = w >> 2;                 // out c-tile pair {2hh, 2hh+1}
    const int nn   = lane & 15;
    const int q8   = (lane >> 4) << 3;       // K=32 k-offset within fragment
    const int q4   = (lane >> 4) << 2;       // K=16 k-offset / C-D row base
    const int b0   = r4 >> 1;                // m-band: m-tiles 2b0..2b0+3

    // tabs phase offsets (uint4 units): pos = (u&7)*20 + (u>>3)
    const int rr   = r4 * 16 + nn;                    // pass-B out row
    const int u0F  = q4 - rr + 64;                    // F taps, K=16 frags
    const int offF = (u0F & 7) * 20 + (u0F >> 3);
    const int cG0  = 2 * hh * 16 + nn;                // pass-A col, ct0
    const int uG0  = q8 - cG0 + 64;
    const int uG1  = uG0 - 16;                        // ct1 = ct0 + 16 cols
    const int offG0 = (uG0 & 7) * 20 + (uG0 >> 3);
    const int offG1 = (uG1 & 7) * 20 + (uG1 >> 3);

    // ---- stage gray = 3-channel mean (f16), float4 loads, group bounds ----
    {
        const float* c0p = x + (size_t)n * 3 * IMG * IMG;
        const float* c1p = c0p + IMG * IMG;
        const float* c2p = c0p + 2 * IMG * IMG;
        for (int e = tid; e < 96 * 24; e += 512) {
            int hr = e / 24, g4 = e - hr * 24;
            int hc0 = g4 * 4;
            int gr = r0g + hr, gc0 = c0g + hc0;
            float4 v = make_float4(0.f, 0.f, 0.f, 0.f);
            if (hr < 95 && (unsigned)gr < IMG && (unsigned)gc0 < IMG) {
                size_t off = ((size_t)gr * IMG + gc0) >> 2;
                float4 a = ((const float4*)c0p)[off];
                float4 b = ((const float4*)c1p)[off];
                float4 c = ((const float4*)c2p)[off];
                v.x = (a.x + b.x + c.x) * (1.0f / 3.0f);
                v.y = (a.y + b.y + c.y) * (1.0f / 3.0f);
                v.z = (a.z + b.z + c.z) * (1.0f / 3.0f);
                v.w = (hc0 == 92) ? 0.0f : (a.w + b.w + c.w) * (1.0f / 3.0f);
            }
            uint2 w2;
            w2.x = pkrtz(v.x, v.y);
            w2.y = pkrtz(v.z, v.w);
            *(uint2*)(&gray[hr * GS + hc0]) = w2;
        }
    }
    __syncthreads();      // the ONLY barrier

    // ---- fused S0: 16x16 avg-pool of gray interior ----
    if (tid < 256) {
        int cell = tid >> 4, sub = tid & 15;
        int pr = cell >> 2, pc = cell & 3;
        const _Float16* row = &gray[(16 + pr * 16 + sub) * GS + 16 + pc * 16];
        float s = 0.0f;
        #pragma unroll
        for (int j = 0; j < 16; ++j) s += (float)row[j];
        s += __shfl_xor(s, 1);
        s += __shfl_xor(s, 2);
        s += __shfl_xor(s, 4);
        s += __shfl_xor(s, 8);
        if (sub == 0)
            s0out[(size_t)n * 1024 + (ty * 4 + pr) * 32 + (tx * 4 + pc)] = s * (1.0f / 256.0f);
    }

    // ---- gray A-fragments for THIS wave's band: m-tiles 2b0..2b0+3,
    //      k-blocks hh..hh+1 (cols needed by c-tiles 2hh..2hh+1) ----
    v8h Agray[4][2];
    #pragma unroll
    for (int mi = 0; mi < 4; ++mi)
        #pragma unroll
        for (int jj = 0; jj < 2; ++jj)
            Agray[mi][jj] = *(const v8h*)(&gray[((2 * b0 + mi) * 16 + nn) * GS + (hh + jj) * 32 + q8]);

    float* s1b = s1out + (size_t)n * NFILT * 1024;

    // magnitude + full-tile pool + direct global store (no LDS)
    auto magstore = [&](v4f P1, v4f P2, v4f P3, v4f P4, int faI, int fbI, int ct) {
        v4f are = P1 - P2, aim = P3 + P4;
        v4f bre = P1 + P2, bim = P3 - P4;
        float sa0 = fsqrt(fmaf(are[0], are[0], fmaf(aim[0], aim[0], 1e-8f)));
        float sa1 = fsqrt(fmaf(are[1], are[1], fmaf(aim[1], aim[1], 1e-8f)));
        float sa2 = fsqrt(fmaf(are[2], are[2], fmaf(aim[2], aim[2], 1e-8f)));
        float sa3 = fsqrt(fmaf(are[3], are[3], fmaf(aim[3], aim[3], 1e-8f)));
        float sb0 = fsqrt(fmaf(bre[0], bre[0], fmaf(bim[0], bim[0], 1e-8f)));
        float sb1 = fsqrt(fmaf(bre[1], bre[1], fmaf(bim[1], bim[1], 1e-8f)));
        float sb2 = fsqrt(fmaf(bre[2], bre[2], fmaf(bim[2], bim[2], 1e-8f)));
        float sb3 = fsqrt(fmaf(bre[3], bre[3], fmaf(bim[3], bim[3], 1e-8f)));
        float ma = (sa0 + sa1) + (sa2 + sa3);
        float mb = (sb0 + sb1) + (sb2 + sb3);
        ma = dpp_add<0xB1>(ma);   mb = dpp_add<0xB1>(mb);   // quad_perm xor1
        ma = dpp_add<0x4E>(ma);   mb = dpp_add<0x4E>(mb);   // quad_perm xor2
        ma = dpp_add<0x141>(ma);  mb = dpp_add<0x141>(mb);  // row_half_mirror
        ma = dpp_add<0x140>(ma);  mb = dpp_add<0x140>(mb);  // row_mirror
        ma += __shfl_xor(ma, 16); mb += __shfl_xor(mb, 16);
        ma += __shfl_xor(ma, 32); mb += __shfl_xor(mb, 32);
        if (lane == 0) {
            s1b[((size_t)faI * 32 + (ty * 4 + r4)) * 32 + (tx * 4 + ct)] = ma * (1.0f / 256.0f);
            s1b[((size_t)fbI * 32 + (ty * 4 + r4)) * 32 + (tx * 4 + ct)] = mb * (1.0f / 256.0f);
        }
    };

    // ---- main loop over 16 conjugate pairs: NO barriers, waves free-run ----
    for (int p = 0; p < NPAIR; ++p) {
        const int fa  = ((p >> 2) << 3) + (p & 3);
        const int fbi = ((p >> 2) << 3) + 7 - (p & 3);
        const uint4* ft  = tabs + (size_t)fa * 800;
        const uint2* ft2 = (const uint2*)ft;

        // F fragments (K=16): taps u0F + 16*(2b0+s), s = 0..3
        v4h Fr[4], Fi[4];
        #pragma unroll
        for (int s = 0; s < 4; ++s) {
            Fr[s] = ldfrag2(ft2 + 640 + 2 * offF + 8 * b0 + 4 * s);
            Fi[s] = ldfrag2(ft2 + 960 + 2 * offF + 8 * b0 + 4 * s);
        }
        // G fragments for ct0
        v8h Gr[2], Gi[2];
        #pragma unroll
        for (int jj = 0; jj < 2; ++jj) {
            Gr[jj] = ldfrag(ft + offG0 + (hh + jj) * 4);
            Gi[jj] = ldfrag(ft + 160 + offG0 + (hh + jj) * 4);
        }

        // ---- ct0 pass A: T tiles (m-tiles 2b0+mi, col-tile 2hh) in regs ----
        v4h tre[4], tim[4];
        #pragma unroll
        for (int mi = 0; mi < 4; ++mi) {
            v4f aR = {0.f, 0.f, 0.f, 0.f}, aI = {0.f, 0.f, 0.f, 0.f};
            aR = MF32(Agray[mi][0], Gr[0], aR);
            aI = MF32(Agray[mi][0], Gi[0], aI);
            aR = MF32(Agray[mi][1], Gr[1], aR);
            aI = MF32(Agray[mi][1], Gi[1], aI);
            tre[mi] = pk4(aR);
            tim[mi] = pk4(aI);
        }

        // G fragments for ct1: issued now, latency hidden under ct0 pass B
        v8h Gr1[2], Gi1[2];
        #pragma unroll
        for (int jj = 0; jj < 2; ++jj) {
            Gr1[jj] = ldfrag(ft + offG1 + (hh + jj) * 4);
            Gi1[jj] = ldfrag(ft + 160 + offG1 + (hh + jj) * 4);
        }

        // ---- ct0 pass B: K=16 chains, T-frags straight from registers ----
        {
            v4f P1 = {0.f,0.f,0.f,0.f}, P2 = {0.f,0.f,0.f,0.f};
            v4f P3 = {0.f,0.f,0.f,0.f}, P4 = {0.f,0.f,0.f,0.f};
            #pragma unroll
            for (int s = 0; s < 4; ++s) {
                P1 = MF16(Fr[s], tre[s], P1);
                P2 = MF16(Fi[s], tim[s], P2);
                P3 = MF16(Fr[s], tim[s], P3);
                P4 = MF16(Fi[s], tre[s], P4);
            }
            magstore(P1, P2, P3, P4, fa, fbi, 2 * hh);
        }

        // ---- ct1 pass A ----
        #pragma unroll
        for (int mi = 0; mi < 4; ++mi) {
            v4f aR = {0.f, 0.f, 0.f, 0.f}, aI = {0.f, 0.f, 0.f, 0.f};
            aR = MF32(Agray[mi][0], Gr1[0], aR);
            aI = MF32(Agray[mi][0], Gi1[0], aI);
            aR = MF32(Agray[mi][1], Gr1[1], aR);
            aI = MF32(Agray[mi][1], Gi1[1], aI);
            tre[mi] = pk4(aR);
            tim[mi] = pk4(aI);
        }

        // ---- ct1 pass B ----
        {
            v4f P1 = {0.f,0.f,0.f,0.f}, P2 = {0.f,0.f,0.f,0.f};
            v4f P3 = {0.f,0.f,0.f,0.f}, P4 = {0.f,0.f,0.f,0.f};
            #pragma unroll
            for (int s = 0; s < 4; ++s) {
                P1 = MF16(Fr[s], tre[s], P1);
                P2 = MF16(Fi[s], tim[s], P2);
                P3 = MF16(Fr[s], tim[s], P3);
                P4 = MF16(Fi[s], tre[s], P4);
            }
            magstore(P1, P2, P3, P4, fa, fbi, 2 * hh + 1);
        }
    }
}

// ---------------------------------------------------------------------------
extern "C" void kernel_launch(void* const* d_in, const int* in_sizes, int n_in,
                              void* d_out, int out_size, void* d_ws, size_t ws_size,
                              hipStream_t stream) {
    const float* x = (const float*)d_in[0];
    float* out = (float*)d_out;
    unsigned* tabs = (unsigned*)d_ws;          // 102400 dwords = 400 KB scratch

    hipLaunchKernelGGL(make_tables, dim3(32), dim3(256), 0, stream, tabs);
    hipLaunchKernelGGL(conv_kernel, dim3(512), dim3(512), 0, stream,
                       x, (const uint4*)tabs, out, out + 8192);
}